// Round 1
// baseline (672.435 us; speedup 1.0000x reference)
//
#include <hip/hip_runtime.h>
#include <float.h>

#define BATCH 32
#define C_IN 16
#define C_OUT 32
#define NTOK 2048
#define KNN 3

// Kernel 1: transpose x (B, C, N) -> xT (B, N, C) and precompute sq[b][n] = sum_c x^2
// sq recipe must match reference: products rounded (mul), then sequential add over c.
__global__ void __launch_bounds__(256) transpose_sq_kernel(
    const float* __restrict__ x, float* __restrict__ xT, float* __restrict__ sq)
{
    const int n = blockIdx.x * 256 + threadIdx.x;
    const int b = blockIdx.y;
    const float* xb = x + (size_t)b * C_IN * NTOK;

    float v[C_IN];
#pragma unroll
    for (int c = 0; c < C_IN; ++c) v[c] = xb[(size_t)c * NTOK + n];

    float acc = 0.0f;
#pragma unroll
    for (int c = 0; c < C_IN; ++c) acc = __fadd_rn(acc, __fmul_rn(v[c], v[c]));
    sq[(size_t)b * NTOK + n] = acc;

    float4* dst = (float4*)(xT + ((size_t)b * NTOK + n) * C_IN);
#pragma unroll
    for (int j = 0; j < 4; ++j)
        dst[j] = make_float4(v[4 * j + 0], v[4 * j + 1], v[4 * j + 2], v[4 * j + 3]);
}

// Kernel 2: per (b, n): scan all m, keep 3 smallest dist (ties -> lower index),
// then gather the 3 neighbor columns and apply the (C_OUT, C_IN, K) contraction.
__global__ void __launch_bounds__(256) nnconv_kernel(
    const float* __restrict__ xT, const float* __restrict__ sq,
    const float* __restrict__ W, const float* __restrict__ bias,
    float* __restrict__ out)
{
    const int n = blockIdx.x * 256 + threadIdx.x;
    const int b = blockIdx.y;
    const float* xb  = xT + (size_t)b * NTOK * C_IN;
    const float* sqb = sq + (size_t)b * NTOK;

    // own column into registers
    float xn[C_IN];
    {
        const float4* src = (const float4*)(xb + (size_t)n * C_IN);
#pragma unroll
        for (int j = 0; j < 4; ++j) {
            float4 t = src[j];
            xn[4 * j + 0] = t.x; xn[4 * j + 1] = t.y;
            xn[4 * j + 2] = t.z; xn[4 * j + 3] = t.w;
        }
    }
    const float sqn = sqb[n];

    float d0 = FLT_MAX, d1 = FLT_MAX, d2 = FLT_MAX;
    int   i0 = 0,       i1 = 0,       i2 = 0;

#pragma unroll 4
    for (int m = 0; m < NTOK; ++m) {
        const float4* xm4 = (const float4*)(xb + (size_t)m * C_IN);
        float4 a0 = xm4[0], a1 = xm4[1], a2 = xm4[2], a3 = xm4[3];

        // gram: sequential FMA over c (matches dot-product reduction)
        float g = 0.0f;
        g = __fmaf_rn(xn[0],  a0.x, g); g = __fmaf_rn(xn[1],  a0.y, g);
        g = __fmaf_rn(xn[2],  a0.z, g); g = __fmaf_rn(xn[3],  a0.w, g);
        g = __fmaf_rn(xn[4],  a1.x, g); g = __fmaf_rn(xn[5],  a1.y, g);
        g = __fmaf_rn(xn[6],  a1.z, g); g = __fmaf_rn(xn[7],  a1.w, g);
        g = __fmaf_rn(xn[8],  a2.x, g); g = __fmaf_rn(xn[9],  a2.y, g);
        g = __fmaf_rn(xn[10], a2.z, g); g = __fmaf_rn(xn[11], a2.w, g);
        g = __fmaf_rn(xn[12], a3.x, g); g = __fmaf_rn(xn[13], a3.y, g);
        g = __fmaf_rn(xn[14], a3.z, g); g = __fmaf_rn(xn[15], a3.w, g);

        // dist = (sq_n - 2*g) + sq_m, each op individually rounded (match ref)
        float d = __fadd_rn(__fsub_rn(sqn, __fmul_rn(2.0f, g)), sqb[m]);

        // stable top-3 insertion: strict < keeps earlier (lower) index on ties,
        // matching jax.lax.top_k tie-break.
        if (d < d2) {
            if (d < d1) {
                d2 = d1; i2 = i1;
                if (d < d0) { d1 = d0; i1 = i0; d0 = d; i0 = m; }
                else        { d1 = d;  i1 = m; }
            } else { d2 = d; i2 = m; }
        }
    }

    // gather the 3 neighbor columns
    float xg[KNN][C_IN];
    const int idx[KNN] = { i0, i1, i2 };
#pragma unroll
    for (int k = 0; k < KNN; ++k) {
        const float4* src = (const float4*)(xb + (size_t)idx[k] * C_IN);
#pragma unroll
        for (int j = 0; j < 4; ++j) {
            float4 t = src[j];
            xg[k][4 * j + 0] = t.x; xg[k][4 * j + 1] = t.y;
            xg[k][4 * j + 2] = t.z; xg[k][4 * j + 3] = t.w;
        }
    }

    // conv epilogue: out[b][o][n] = bias[o] + sum_{c,k} W[o][c][k] * xg[k][c]
#pragma unroll
    for (int o = 0; o < C_OUT; ++o) {
        float acc = bias[o];
#pragma unroll
        for (int c = 0; c < C_IN; ++c) {
#pragma unroll
            for (int k = 0; k < KNN; ++k)
                acc = __fmaf_rn(W[(o * C_IN + c) * KNN + k], xg[k][c], acc);
        }
        out[((size_t)b * C_OUT + o) * NTOK + n] = acc;
    }
}

extern "C" void kernel_launch(void* const* d_in, const int* in_sizes, int n_in,
                              void* d_out, int out_size, void* d_ws, size_t ws_size,
                              hipStream_t stream) {
    const float* x    = (const float*)d_in[0];
    const float* W    = (const float*)d_in[1];
    const float* bias = (const float*)d_in[2];
    float* out = (float*)d_out;

    float* xT = (float*)d_ws;                          // B*N*C floats = 4 MB
    float* sq = xT + (size_t)BATCH * NTOK * C_IN;      // B*N floats = 256 KB

    dim3 grid(NTOK / 256, BATCH);
    transpose_sq_kernel<<<grid, 256, 0, stream>>>(x, xT, sq);
    nnconv_kernel<<<grid, 256, 0, stream>>>(xT, sq, W, bias, out);
}

// Round 2
// 157.413 us; speedup vs baseline: 4.2718x; 4.2718x over previous
//
#include <hip/hip_runtime.h>
#include <float.h>

#define BATCH 32
#define C_IN 16
#define C_OUT 32
#define NTOK 2048
#define KNN 3

#define TILE_M 256
#define MSEG (NTOK / 2)          // each thread-group scans half the m range
#define NTILE (MSEG / TILE_M)    // tiles per group

// Kernel 1: transpose x (B, C, N) -> xT (B, N, C) and precompute sq[b][n].
// sq recipe matches reference: rounded mul, then sequential add over c.
__global__ void __launch_bounds__(256) transpose_sq_kernel(
    const float* __restrict__ x, float* __restrict__ xT, float* __restrict__ sq)
{
    const int n = blockIdx.x * 256 + threadIdx.x;
    const int b = blockIdx.y;
    const float* xb = x + (size_t)b * C_IN * NTOK;

    float v[C_IN];
#pragma unroll
    for (int c = 0; c < C_IN; ++c) v[c] = xb[(size_t)c * NTOK + n];

    float acc = 0.0f;
#pragma unroll
    for (int c = 0; c < C_IN; ++c) acc = __fadd_rn(acc, __fmul_rn(v[c], v[c]));
    sq[(size_t)b * NTOK + n] = acc;

    float4* dst = (float4*)(xT + ((size_t)b * NTOK + n) * C_IN);
#pragma unroll
    for (int j = 0; j < 4; ++j)
        dst[j] = make_float4(v[4 * j + 0], v[4 * j + 1], v[4 * j + 2], v[4 * j + 3]);
}

// Kernel 2: 512 threads/block. Group g (= tid>>8) scans m in [g*1024, (g+1)*1024)
// over LDS-staged 256-column tiles; per-(b,n) top-3 lists are merged in LDS.
__global__ void __launch_bounds__(512) nnconv_kernel(
    const float* __restrict__ xT, const float* __restrict__ sq,
    const float* __restrict__ W, const float* __restrict__ bias,
    float* __restrict__ out)
{
    __shared__ float lds_x[2][TILE_M * C_IN];   // 2 x 16 KB
    __shared__ float lds_sq[2][TILE_M];         // 2 x 1 KB
    __shared__ float lds_d[3][256];
    __shared__ int   lds_i[3][256];

    const int tid = threadIdx.x;
    const int g   = tid >> 8;      // 0 or 1
    const int lid = tid & 255;
    const int n = blockIdx.x * 256 + lid;
    const int b = blockIdx.y;
    const float* xb  = xT + (size_t)b * NTOK * C_IN;
    const float* sqb = sq + (size_t)b * NTOK;

    // own column into registers
    float xn[C_IN];
    {
        const float4* src = (const float4*)(xb + (size_t)n * C_IN);
#pragma unroll
        for (int j = 0; j < 4; ++j) {
            float4 t = src[j];
            xn[4 * j + 0] = t.x; xn[4 * j + 1] = t.y;
            xn[4 * j + 2] = t.z; xn[4 * j + 3] = t.w;
        }
    }
    const float sqn = sqb[n];

    float d0 = FLT_MAX, d1 = FLT_MAX, d2 = FLT_MAX;
    int   i0 = 0,       i1 = 0,       i2 = 0;

    const int mbase0 = g * MSEG;
    for (int t = 0; t < NTILE; ++t) {
        const int mbase = mbase0 + t * TILE_M;
        __syncthreads();
        // stage this group's tile (coalesced float4 copies)
        {
            const float4* gsrc = (const float4*)(xb + (size_t)mbase * C_IN);
            float4* ldst = (float4*)lds_x[g];
#pragma unroll
            for (int j = 0; j < 4; ++j)
                ldst[lid + 256 * j] = gsrc[lid + 256 * j];
            if (lid < TILE_M / 4)
                ((float4*)lds_sq[g])[lid] = ((const float4*)(sqb + mbase))[lid];
        }
        __syncthreads();

        const float* lx  = lds_x[g];
        const float* lsq = lds_sq[g];
#pragma unroll 4
        for (int mm = 0; mm < TILE_M; ++mm) {
            const float4* xm4 = (const float4*)(lx + mm * C_IN);
            float4 a0 = xm4[0], a1 = xm4[1], a2 = xm4[2], a3 = xm4[3];

            float gs = 0.0f;
            gs = __fmaf_rn(xn[0],  a0.x, gs); gs = __fmaf_rn(xn[1],  a0.y, gs);
            gs = __fmaf_rn(xn[2],  a0.z, gs); gs = __fmaf_rn(xn[3],  a0.w, gs);
            gs = __fmaf_rn(xn[4],  a1.x, gs); gs = __fmaf_rn(xn[5],  a1.y, gs);
            gs = __fmaf_rn(xn[6],  a1.z, gs); gs = __fmaf_rn(xn[7],  a1.w, gs);
            gs = __fmaf_rn(xn[8],  a2.x, gs); gs = __fmaf_rn(xn[9],  a2.y, gs);
            gs = __fmaf_rn(xn[10], a2.z, gs); gs = __fmaf_rn(xn[11], a2.w, gs);
            gs = __fmaf_rn(xn[12], a3.x, gs); gs = __fmaf_rn(xn[13], a3.y, gs);
            gs = __fmaf_rn(xn[14], a3.z, gs); gs = __fmaf_rn(xn[15], a3.w, gs);

            float d = __fadd_rn(__fsub_rn(sqn, __fmul_rn(2.0f, gs)), lsq[mm]);
            const int m = mbase + mm;
            if (d < d2) {
                if (d < d1) {
                    d2 = d1; i2 = i1;
                    if (d < d0) { d1 = d0; i1 = i0; d0 = d; i0 = m; }
                    else        { d1 = d;  i1 = m; }
                } else { d2 = d; i2 = m; }
            }
        }
    }

    // merge the two groups' top-3 lists (group 1 indices are all larger,
    // strict < keeps the earlier-index winner on ties -> matches full scan)
    __syncthreads();
    if (g == 1) {
        lds_d[0][lid] = d0; lds_d[1][lid] = d1; lds_d[2][lid] = d2;
        lds_i[0][lid] = i0; lds_i[1][lid] = i1; lds_i[2][lid] = i2;
    }
    __syncthreads();
    if (g == 0) {
#pragma unroll
        for (int k = 0; k < KNN; ++k) {
            float dc = lds_d[k][lid]; int ic = lds_i[k][lid];
            if (dc < d2) {
                if (dc < d1) {
                    d2 = d1; i2 = i1;
                    if (dc < d0) { d1 = d0; i1 = i0; d0 = dc; i0 = ic; }
                    else         { d1 = dc; i1 = ic; }
                } else { d2 = dc; i2 = ic; }
            }
        }

        // gather the 3 neighbor columns
        float xg[KNN][C_IN];
        const int idx[KNN] = { i0, i1, i2 };
#pragma unroll
        for (int k = 0; k < KNN; ++k) {
            const float4* src = (const float4*)(xb + (size_t)idx[k] * C_IN);
#pragma unroll
            for (int j = 0; j < 4; ++j) {
                float4 t = src[j];
                xg[k][4 * j + 0] = t.x; xg[k][4 * j + 1] = t.y;
                xg[k][4 * j + 2] = t.z; xg[k][4 * j + 3] = t.w;
            }
        }

        // conv epilogue: out[b][o][n] = bias[o] + sum_{c,k} W[o][c][k] * xg[k][c]
#pragma unroll
        for (int o = 0; o < C_OUT; ++o) {
            float acc = bias[o];
#pragma unroll
            for (int c = 0; c < C_IN; ++c) {
#pragma unroll
                for (int k = 0; k < KNN; ++k)
                    acc = __fmaf_rn(W[(o * C_IN + c) * KNN + k], xg[k][c], acc);
            }
            out[((size_t)b * C_OUT + o) * NTOK + n] = acc;
        }
    }
}

extern "C" void kernel_launch(void* const* d_in, const int* in_sizes, int n_in,
                              void* d_out, int out_size, void* d_ws, size_t ws_size,
                              hipStream_t stream) {
    const float* x    = (const float*)d_in[0];
    const float* W    = (const float*)d_in[1];
    const float* bias = (const float*)d_in[2];
    float* out = (float*)d_out;

    float* xT = (float*)d_ws;                          // B*N*C floats = 4 MB
    float* sq = xT + (size_t)BATCH * NTOK * C_IN;      // B*N floats = 256 KB

    dim3 grid1(NTOK / 256, BATCH);
    transpose_sq_kernel<<<grid1, 256, 0, stream>>>(x, xT, sq);
    dim3 grid2(NTOK / 256, BATCH);
    nnconv_kernel<<<grid2, 512, 0, stream>>>(xT, sq, W, bias, out);
}

// Round 3
// 138.768 us; speedup vs baseline: 4.8457x; 1.1344x over previous
//
#include <hip/hip_runtime.h>
#include <float.h>

#define BATCH 32
#define C_IN 16
#define C_OUT 32
#define NTOK 2048
#define KNN 3

#define NSEG 16              // total m-segments
#define SEGM (NTOK / NSEG)   // 128 m per segment
#define ZBLK (NSEG / 2)      // 8 z-blocks; each block handles 2 segments (one per group)
#define GLAN 128             // lanes per group
#define RN 8                 // n-columns per thread

typedef float float2v __attribute__((ext_vector_type(2)));

union Quad { float4 f4; float2v h[2]; };

// Kernel 1: transpose x (B,C,N) -> xT (B,N,C), sq[b][n] = sum_c x^2 (rounded mul, seq add)
__global__ void __launch_bounds__(256) transpose_sq_kernel(
    const float* __restrict__ x, float* __restrict__ xT, float* __restrict__ sq)
{
    const int n = blockIdx.x * 256 + threadIdx.x;
    const int b = blockIdx.y;
    const float* xb = x + (size_t)b * C_IN * NTOK;

    float v[C_IN];
#pragma unroll
    for (int c = 0; c < C_IN; ++c) v[c] = xb[(size_t)c * NTOK + n];

    float acc = 0.0f;
#pragma unroll
    for (int c = 0; c < C_IN; ++c) acc = __fadd_rn(acc, __fmul_rn(v[c], v[c]));
    sq[(size_t)b * NTOK + n] = acc;

    float4* dst = (float4*)(xT + ((size_t)b * NTOK + n) * C_IN);
#pragma unroll
    for (int j = 0; j < 4; ++j)
        dst[j] = make_float4(v[4 * j + 0], v[4 * j + 1], v[4 * j + 2], v[4 * j + 3]);
}

// branchless tie-exact top-3 insert (strict <: on equal d, earlier index wins)
#define INSERT(r, dv, iv) {                                        \
    const float od0 = d0[r], od1 = d1[r], od2 = d2[r];             \
    const int   oi0 = i0[r], oi1 = i1[r], oi2 = i2[r];             \
    const bool c0 = (dv) < od0, c1 = (dv) < od1, c2 = (dv) < od2;  \
    d0[r] = fminf((dv), od0);                                      \
    d1[r] = fminf(fmaxf((dv), od0), od1);                          \
    d2[r] = fminf(fmaxf((dv), od1), od2);                          \
    i0[r] = c0 ? (iv) : oi0;                                       \
    i1[r] = c0 ? oi0  : (c1 ? (iv) : oi1);                         \
    i2[r] = c1 ? oi1  : (c2 ? (iv) : oi2); }

// Kernel 2: per block: 2 groups x 128 lanes; group g scans segment z*2+g (128 m's,
// LDS-staged). Each thread owns 8 n's (4 packed pairs). In-block merge, then write
// per-z partial top-3 lists to workspace (SoA: comp k in 0..5, k>=3 are int bits).
__global__ void __launch_bounds__(256, 2) knn_partial_kernel(
    const float* __restrict__ xT, const float* __restrict__ sq,
    float* __restrict__ part)
{
    __shared__ float lds_x[2][SEGM * C_IN];   // 2 x 8 KB
    __shared__ float lds_sq[2][SEGM];         // 2 x 0.5 KB
    __shared__ float lds_m[6][GLAN * RN];     // 24 KB merge buffer

    const int tid = threadIdx.x;
    const int g   = tid >> 7;
    const int lid = tid & (GLAN - 1);
    const int b = blockIdx.y;
    const int z = blockIdx.z;
    const int nbase = blockIdx.x * (GLAN * RN);
    const int mbase = (z * 2 + g) * SEGM;

    const float* xb  = xT + (size_t)b * NTOK * C_IN;
    const float* sqb = sq + (size_t)b * NTOK;

    // own 8 columns as 4 n-pairs: pair q = (n_{2q} in lo, n_{2q+1} in hi)
    float2v xn2[4][C_IN];
    float sqn[RN];
#pragma unroll
    for (int q = 0; q < 4; ++q) {
        const int na = nbase + (2 * q)     * GLAN + lid;
        const int nb = nbase + (2 * q + 1) * GLAN + lid;
        const float4* ra = (const float4*)(xb + (size_t)na * C_IN);
        const float4* rb = (const float4*)(xb + (size_t)nb * C_IN);
#pragma unroll
        for (int j = 0; j < 4; ++j) {
            float4 ta = ra[j], tb = rb[j];
            xn2[q][4 * j + 0] = float2v{ta.x, tb.x};
            xn2[q][4 * j + 1] = float2v{ta.y, tb.y};
            xn2[q][4 * j + 2] = float2v{ta.z, tb.z};
            xn2[q][4 * j + 3] = float2v{ta.w, tb.w};
        }
        sqn[2 * q]     = sqb[na];
        sqn[2 * q + 1] = sqb[nb];
    }

    // stage this group's 128-m tile
    {
        const float4* gsrc = (const float4*)(xb + (size_t)mbase * C_IN);
        float4* ldst = (float4*)lds_x[g];
#pragma unroll
        for (int j = 0; j < 4; ++j)
            ldst[lid + GLAN * j] = gsrc[lid + GLAN * j];
        lds_sq[g][lid] = sqb[mbase + lid];
    }
    __syncthreads();

    float d0[RN], d1[RN], d2[RN];
    int   i0[RN], i1[RN], i2[RN];
#pragma unroll
    for (int r = 0; r < RN; ++r) {
        d0[r] = FLT_MAX; d1[r] = FLT_MAX; d2[r] = FLT_MAX;
        i0[r] = 0; i1[r] = 0; i2[r] = 0;
    }

    const float* lx  = lds_x[g];
    const float* lsq = lds_sq[g];

#pragma unroll 2
    for (int mm = 0; mm < SEGM; ++mm) {
        const float4* r4 = (const float4*)(lx + mm * C_IN);
        Quad A[4];
        A[0].f4 = r4[0]; A[1].f4 = r4[1]; A[2].f4 = r4[2]; A[3].f4 = r4[3];
        const float sqm = lsq[mm];
        const int m = mbase + mm;

        float2v gq[4];
#pragma unroll
        for (int q = 0; q < 4; ++q) gq[q] = float2v{0.0f, 0.0f};

        // sequential c-chain (c = 0..15) per n, bitexact to scalar __fmaf_rn chain.
        // src1 = packed (a[c], a[c+1]); op_sel picks lo (even c) / hi (odd c) for
        // BOTH result halves -> broadcast of the wave-uniform xm element.
#pragma unroll
        for (int p = 0; p < 8; ++p) {
            const float2v ap = A[p >> 1].h[p & 1];   // (a[2p], a[2p+1])
#pragma unroll
            for (int q = 0; q < 4; ++q) {
                asm("v_pk_fma_f32 %0, %1, %2, %0 op_sel:[0,0,0] op_sel_hi:[1,0,1]"
                    : "+v"(gq[q]) : "v"(xn2[q][2 * p]), "v"(ap));
                asm("v_pk_fma_f32 %0, %1, %2, %0 op_sel:[0,1,0] op_sel_hi:[1,1,1]"
                    : "+v"(gq[q]) : "v"(xn2[q][2 * p + 1]), "v"(ap));
            }
        }

#pragma unroll
        for (int q = 0; q < 4; ++q) {
            const float gl = gq[q].x, gh = gq[q].y;
            const float dl = __fadd_rn(__fsub_rn(sqn[2 * q],     __fmul_rn(2.0f, gl)), sqm);
            const float dh = __fadd_rn(__fsub_rn(sqn[2 * q + 1], __fmul_rn(2.0f, gh)), sqm);
            INSERT(2 * q,     dl, m);
            INSERT(2 * q + 1, dh, m);
        }
    }

    // in-block merge: group 0 (lower m-range) absorbs group 1's lists (higher m,
    // strict < keeps earlier index -> identical to streaming both segments in order)
    __syncthreads();
    if (g == 1) {
#pragma unroll
        for (int r = 0; r < RN; ++r) {
            const int nn = r * GLAN + lid;
            lds_m[0][nn] = d0[r]; lds_m[1][nn] = d1[r]; lds_m[2][nn] = d2[r];
            lds_m[3][nn] = __int_as_float(i0[r]);
            lds_m[4][nn] = __int_as_float(i1[r]);
            lds_m[5][nn] = __int_as_float(i2[r]);
        }
    }
    __syncthreads();
    if (g == 0) {
#pragma unroll
        for (int r = 0; r < RN; ++r) {
            const int nn = r * GLAN + lid;
#pragma unroll
            for (int k = 0; k < KNN; ++k) {
                const float dc = lds_m[k][nn];
                const int   ic = __float_as_int(lds_m[3 + k][nn]);
                INSERT(r, dc, ic);
            }
            // write partial list: part[((k*ZBLK + z)*BATCH + b)*NTOK + n]
            const int n = nbase + nn;
            const size_t stride = (size_t)ZBLK * BATCH * NTOK;
            const size_t base = ((size_t)z * BATCH + b) * NTOK + n;
            part[base + 0 * stride] = d0[r];
            part[base + 1 * stride] = d1[r];
            part[base + 2 * stride] = d2[r];
            part[base + 3 * stride] = __int_as_float(i0[r]);
            part[base + 4 * stride] = __int_as_float(i1[r]);
            part[base + 5 * stride] = __int_as_float(i2[r]);
        }
    }
}

// Kernel 3: merge the ZBLK partial lists per n (ascending z = ascending m-range,
// strict < keeps earlier index), gather 3 neighbor columns, conv epilogue.
__global__ void __launch_bounds__(256) merge_conv_kernel(
    const float* __restrict__ xT, const float* __restrict__ part,
    const float* __restrict__ W, const float* __restrict__ bias,
    float* __restrict__ out)
{
    const int n = blockIdx.x * 256 + threadIdx.x;
    const int b = blockIdx.y;

    float D0 = FLT_MAX, D1 = FLT_MAX, D2 = FLT_MAX;
    int   I0 = 0,       I1 = 0,       I2 = 0;

    const size_t stride = (size_t)ZBLK * BATCH * NTOK;
#pragma unroll
    for (int z = 0; z < ZBLK; ++z) {
        const size_t base = ((size_t)z * BATCH + b) * NTOK + n;
#pragma unroll
        for (int k = 0; k < KNN; ++k) {
            const float dc = part[base + (size_t)k * stride];
            const int   ic = __float_as_int(part[base + (size_t)(3 + k) * stride]);
            const bool c0 = dc < D0, c1 = dc < D1, c2 = dc < D2;
            const float nd0 = fminf(dc, D0);
            const float nd1 = fminf(fmaxf(dc, D0), D1);
            const float nd2 = fminf(fmaxf(dc, D1), D2);
            I2 = c1 ? I1 : (c2 ? ic : I2);
            I1 = c0 ? I0 : (c1 ? ic : I1);
            I0 = c0 ? ic : I0;
            D0 = nd0; D1 = nd1; D2 = nd2;
        }
    }

    const float* xb = xT + (size_t)b * NTOK * C_IN;
    float xg[KNN][C_IN];
    const int idx[KNN] = { I0, I1, I2 };
#pragma unroll
    for (int k = 0; k < KNN; ++k) {
        const float4* src = (const float4*)(xb + (size_t)idx[k] * C_IN);
#pragma unroll
        for (int j = 0; j < 4; ++j) {
            float4 t = src[j];
            xg[k][4 * j + 0] = t.x; xg[k][4 * j + 1] = t.y;
            xg[k][4 * j + 2] = t.z; xg[k][4 * j + 3] = t.w;
        }
    }

#pragma unroll
    for (int o = 0; o < C_OUT; ++o) {
        float acc = bias[o];
#pragma unroll
        for (int c = 0; c < C_IN; ++c) {
#pragma unroll
            for (int k = 0; k < KNN; ++k)
                acc = __fmaf_rn(W[(o * C_IN + c) * KNN + k], xg[k][c], acc);
        }
        out[((size_t)b * C_OUT + o) * NTOK + n] = acc;
    }
}

extern "C" void kernel_launch(void* const* d_in, const int* in_sizes, int n_in,
                              void* d_out, int out_size, void* d_ws, size_t ws_size,
                              hipStream_t stream) {
    const float* x    = (const float*)d_in[0];
    const float* W    = (const float*)d_in[1];
    const float* bias = (const float*)d_in[2];
    float* out = (float*)d_out;

    float* xT   = (float*)d_ws;                                  // 4 MB
    float* sq   = xT + (size_t)BATCH * NTOK * C_IN;              // 256 KB
    float* part = sq + (size_t)BATCH * NTOK;                     // 12.6 MB

    dim3 grid1(NTOK / 256, BATCH);
    transpose_sq_kernel<<<grid1, 256, 0, stream>>>(x, xT, sq);

    dim3 grid2(NTOK / (GLAN * RN), BATCH, ZBLK);
    knn_partial_kernel<<<grid2, 256, 0, stream>>>(xT, sq, part);

    dim3 grid3(NTOK / 256, BATCH);
    merge_conv_kernel<<<grid3, 256, 0, stream>>>(xT, part, W, bias, out);
}

// Round 4
// 126.858 us; speedup vs baseline: 5.3007x; 1.0939x over previous
//
#include <hip/hip_runtime.h>
#include <float.h>

#define BATCH 32
#define C_IN 16
#define C_OUT 32
#define NTOK 2048
#define KNN 3

#define RN 4                  // n-columns per thread
#define NCHUNK (256 * RN)     // 1024 n per block

// Kernel 1: transpose x (B,C,N) -> xT (B,N,C), sq[b][n] = sum_c x^2 (rounded mul, seq add)
__global__ void __launch_bounds__(256) transpose_sq_kernel(
    const float* __restrict__ x, float* __restrict__ xT, float* __restrict__ sq)
{
    const int n = blockIdx.x * 256 + threadIdx.x;
    const int b = blockIdx.y;
    const float* xb = x + (size_t)b * C_IN * NTOK;

    float v[C_IN];
#pragma unroll
    for (int c = 0; c < C_IN; ++c) v[c] = xb[(size_t)c * NTOK + n];

    float acc = 0.0f;
#pragma unroll
    for (int c = 0; c < C_IN; ++c) acc = __fadd_rn(acc, __fmul_rn(v[c], v[c]));
    sq[(size_t)b * NTOK + n] = acc;

    float4* dst = (float4*)(xT + ((size_t)b * NTOK + n) * C_IN);
#pragma unroll
    for (int j = 0; j < 4; ++j)
        dst[j] = make_float4(v[4 * j + 0], v[4 * j + 1], v[4 * j + 2], v[4 * j + 3]);
}

// Kernel 2: block = 256 threads, RN=4 n's each (n-chunk 1024); scans one SEG-long
// m-segment staged in LDS. Scalar sequential-FMA dot chains (bitexact vs fp32 ref
// recipe), fused dist, med3-based branchless top-3. Partials to ws.
template<int SEG>
__global__ void __launch_bounds__(256, 4) knn_partial_kernel(
    const float* __restrict__ xT, const float* __restrict__ sq,
    float* __restrict__ part)
{
    __shared__ float lds_x[SEG * C_IN];   // SEG=128 -> 8 KB, SEG=256 -> 16 KB

    const int tid = threadIdx.x;
    const int b = blockIdx.y;
    const int z = blockIdx.z;
    const int nbase = blockIdx.x * NCHUNK;
    const int mbase = z * SEG;

    const float* xb  = xT + (size_t)b * NTOK * C_IN;
    const float* sqb = sq + (size_t)b * NTOK;

    // stage the m-tile: SEG*4 float4's, 256 threads
    {
        const float4* gsrc = (const float4*)(xb + (size_t)mbase * C_IN);
        float4* ldst = (float4*)lds_x;
#pragma unroll
        for (int j = 0; j < SEG / 64; ++j)
            ldst[tid + 256 * j] = gsrc[tid + 256 * j];
    }

    // own columns
    float xn[RN][C_IN];
    float sqn[RN];
#pragma unroll
    for (int q = 0; q < RN; ++q) {
        const int n = nbase + q * 256 + tid;
        const float4* src = (const float4*)(xb + (size_t)n * C_IN);
#pragma unroll
        for (int j = 0; j < 4; ++j) {
            float4 t = src[j];
            xn[q][4 * j + 0] = t.x; xn[q][4 * j + 1] = t.y;
            xn[q][4 * j + 2] = t.z; xn[q][4 * j + 3] = t.w;
        }
        sqn[q] = sqb[n];
    }
    __syncthreads();

    float d0[RN], d1[RN], d2[RN];
    int   i0[RN], i1[RN], i2[RN];
#pragma unroll
    for (int q = 0; q < RN; ++q) {
        d0[q] = FLT_MAX; d1[q] = FLT_MAX; d2[q] = FLT_MAX;
        i0[q] = 0; i1[q] = 0; i2[q] = 0;
    }

#pragma unroll 2
    for (int mm = 0; mm < SEG; ++mm) {
        const float4* r4 = (const float4*)(lds_x + mm * C_IN);
        const float4 A0 = r4[0], A1 = r4[1], A2 = r4[2], A3 = r4[3];
        const float sqm = sqb[mbase + mm];   // wave-uniform -> scalar load path
        const int m = mbase + mm;

#pragma unroll
        for (int q = 0; q < RN; ++q) {
            // sequential c-chain, bitexact to the fp32 recipe
            float g = 0.0f;
            g = __fmaf_rn(xn[q][0],  A0.x, g); g = __fmaf_rn(xn[q][1],  A0.y, g);
            g = __fmaf_rn(xn[q][2],  A0.z, g); g = __fmaf_rn(xn[q][3],  A0.w, g);
            g = __fmaf_rn(xn[q][4],  A1.x, g); g = __fmaf_rn(xn[q][5],  A1.y, g);
            g = __fmaf_rn(xn[q][6],  A1.z, g); g = __fmaf_rn(xn[q][7],  A1.w, g);
            g = __fmaf_rn(xn[q][8],  A2.x, g); g = __fmaf_rn(xn[q][9],  A2.y, g);
            g = __fmaf_rn(xn[q][10], A2.z, g); g = __fmaf_rn(xn[q][11], A2.w, g);
            g = __fmaf_rn(xn[q][12], A3.x, g); g = __fmaf_rn(xn[q][13], A3.y, g);
            g = __fmaf_rn(xn[q][14], A3.z, g); g = __fmaf_rn(xn[q][15], A3.w, g);

            // (sqn - 2g) + sqm ; fma(-2,g,sqn) is bitexact to sub(sqn, mul(2,g))
            const float d = __fadd_rn(__fmaf_rn(-2.0f, g, sqn[q]), sqm);

            // branchless tie-exact top-3 insert (strict <: earlier index wins ties)
            const bool c0 = d < d0[q], c1 = d < d1[q], c2 = d < d2[q];
            const float od0 = d0[q], od1 = d1[q];
            const int   oi0 = i0[q], oi1 = i1[q];
            d0[q] = fminf(d, d0[q]);
            d1[q] = __builtin_amdgcn_fmed3f(d, od0, d1[q]);
            d2[q] = __builtin_amdgcn_fmed3f(d, od1, d2[q]);
            i0[q] = c0 ? m : i0[q];
            i1[q] = c0 ? oi0 : (c1 ? m : i1[q]);
            i2[q] = c1 ? oi1 : (c2 ? m : i2[q]);
        }
    }

    // write partial lists: part[((k*Z + z)*BATCH + b)*NTOK + n], Z = NTOK/SEG
    const size_t stride = (size_t)(NTOK / SEG) * BATCH * NTOK;
#pragma unroll
    for (int q = 0; q < RN; ++q) {
        const int n = nbase + q * 256 + tid;
        const size_t base = ((size_t)z * BATCH + b) * NTOK + n;
        part[base + 0 * stride] = d0[q];
        part[base + 1 * stride] = d1[q];
        part[base + 2 * stride] = d2[q];
        part[base + 3 * stride] = __int_as_float(i0[q]);
        part[base + 4 * stride] = __int_as_float(i1[q]);
        part[base + 5 * stride] = __int_as_float(i2[q]);
    }
}

// Kernel 3: merge Z partials per n (ascending z = ascending m-range, strict <
// keeps earlier index), gather 3 neighbor columns, conv epilogue.
template<int Z>
__global__ void __launch_bounds__(256) merge_conv_kernel(
    const float* __restrict__ xT, const float* __restrict__ part,
    const float* __restrict__ W, const float* __restrict__ bias,
    float* __restrict__ out)
{
    const int n = blockIdx.x * 256 + threadIdx.x;
    const int b = blockIdx.y;

    float D0 = FLT_MAX, D1 = FLT_MAX, D2 = FLT_MAX;
    int   I0 = 0,       I1 = 0,       I2 = 0;

    const size_t stride = (size_t)Z * BATCH * NTOK;
#pragma unroll
    for (int z = 0; z < Z; ++z) {
        const size_t base = ((size_t)z * BATCH + b) * NTOK + n;
#pragma unroll
        for (int k = 0; k < KNN; ++k) {
            const float dc = part[base + (size_t)k * stride];
            const int   ic = __float_as_int(part[base + (size_t)(3 + k) * stride]);
            const bool c0 = dc < D0, c1 = dc < D1, c2 = dc < D2;
            const float oD0 = D0, oD1 = D1;
            const int   oI0 = I0, oI1 = I1;
            D0 = fminf(dc, D0);
            D1 = __builtin_amdgcn_fmed3f(dc, oD0, D1);
            D2 = __builtin_amdgcn_fmed3f(dc, oD1, D2);
            I0 = c0 ? ic : I0;
            I1 = c0 ? oI0 : (c1 ? ic : I1);
            I2 = c1 ? oI1 : (c2 ? ic : I2);
        }
    }

    const float* xb = xT + (size_t)b * NTOK * C_IN;
    float xg[KNN][C_IN];
    const int idx[KNN] = { I0, I1, I2 };
#pragma unroll
    for (int k = 0; k < KNN; ++k) {
        const float4* src = (const float4*)(xb + (size_t)idx[k] * C_IN);
#pragma unroll
        for (int j = 0; j < 4; ++j) {
            float4 t = src[j];
            xg[k][4 * j + 0] = t.x; xg[k][4 * j + 1] = t.y;
            xg[k][4 * j + 2] = t.z; xg[k][4 * j + 3] = t.w;
        }
    }

#pragma unroll
    for (int o = 0; o < C_OUT; ++o) {
        float acc = bias[o];
#pragma unroll
        for (int c = 0; c < C_IN; ++c) {
#pragma unroll
            for (int k = 0; k < KNN; ++k)
                acc = __fmaf_rn(W[(o * C_IN + c) * KNN + k], xg[k][c], acc);
        }
        out[((size_t)b * C_OUT + o) * NTOK + n] = acc;
    }
}

extern "C" void kernel_launch(void* const* d_in, const int* in_sizes, int n_in,
                              void* d_out, int out_size, void* d_ws, size_t ws_size,
                              hipStream_t stream) {
    const float* x    = (const float*)d_in[0];
    const float* W    = (const float*)d_in[1];
    const float* bias = (const float*)d_in[2];
    float* out = (float*)d_out;

    float* xT   = (float*)d_ws;                                  // 4 MB
    float* sq   = xT + (size_t)BATCH * NTOK * C_IN;              // 256 KB
    float* part = sq + (size_t)BATCH * NTOK;

    const size_t base_bytes = ((size_t)BATCH * NTOK * C_IN + (size_t)BATCH * NTOK) * 4;
    const size_t part16     = 6ull * 16 * BATCH * NTOK * 4;      // 25.2 MB

    dim3 grid1(NTOK / 256, BATCH);
    transpose_sq_kernel<<<grid1, 256, 0, stream>>>(x, xT, sq);

    if (ws_size >= base_bytes + part16) {
        // Z=16: SEG=128 -> 1024 blocks -> 4 waves/SIMD
        dim3 grid2(NTOK / NCHUNK, BATCH, 16);
        knn_partial_kernel<128><<<grid2, 256, 0, stream>>>(xT, sq, part);
        dim3 grid3(NTOK / 256, BATCH);
        merge_conv_kernel<16><<<grid3, 256, 0, stream>>>(xT, part, W, bias, out);
    } else {
        // Z=8: SEG=256 -> 512 blocks (17 MB ws, proven)
        dim3 grid2(NTOK / NCHUNK, BATCH, 8);
        knn_partial_kernel<256><<<grid2, 256, 0, stream>>>(xT, sq, part);
        dim3 grid3(NTOK / 256, BATCH);
        merge_conv_kernel<8><<<grid3, 256, 0, stream>>>(xT, part, W, bias, out);
    }
}